// Round 14
// baseline (15293.324 us; speedup 1.0000x reference)
//
#include <hip/hip_runtime.h>
#include <hip/hip_bf16.h>
#include <hip/hip_fp16.h>

// Problem constants (fixed by the reference)
#define FDIM 128      // F_IN == H == 128
#define G4H  512      // 4*H

typedef float f32x4 __attribute__((ext_vector_type(4)));
typedef _Float16 f16x8 __attribute__((ext_vector_type(8)));

union frag_cast { f32x4 f; f16x8 h; };

// LDS-only barrier: does NOT drain vmcnt (global ops stay in flight).
#define LDS_BARRIER() asm volatile("s_waitcnt lgkmcnt(0)\n\ts_barrier" ::: "memory")

// ---------------------------------------------------------------------------
// degree / normalization
// ---------------------------------------------------------------------------
__global__ void deg_kernel(const int* __restrict__ ei, int* __restrict__ deg, int E) {
    int e = blockIdx.x * 256 + threadIdx.x;
    if (e < E) atomicAdd(&deg[ei[E + e]], 1);
}

__global__ void dinv_kernel(const int* __restrict__ deg, float* __restrict__ dinv, int N) {
    int n = blockIdx.x * 256 + threadIdx.x;
    if (n < N) dinv[n] = rsqrtf((float)(deg[n] + 1));   // +1 self-loop
}

// ---------------------------------------------------------------------------
// CSR build: exclusive scan of deg (1024 thr x 20 nodes), then edge scatter.
// ---------------------------------------------------------------------------
__global__ __launch_bounds__(1024) void scan_kernel(const int* __restrict__ deg,
                                                    int* __restrict__ rs,
                                                    int* __restrict__ cursor,
                                                    int N, int E) {
    __shared__ int buf[2][1024];
    const int t = threadIdx.x;
    const int base = t * 20;
    int loc[20]; int s = 0;
    #pragma unroll
    for (int i = 0; i < 20; ++i) {
        int n = base + i;
        int d = (n < N) ? deg[n] : 0;
        loc[i] = s; s += d;
    }
    buf[0][t] = s; __syncthreads();
    int pb = 0;
    for (int off = 1; off < 1024; off <<= 1) {
        int v = buf[pb][t] + ((t >= off) ? buf[pb][t - off] : 0);
        buf[pb ^ 1][t] = v; pb ^= 1; __syncthreads();
    }
    int pre = (t > 0) ? buf[pb][t - 1] : 0;   // exclusive prefix
    #pragma unroll
    for (int i = 0; i < 20; ++i) {
        int n = base + i;
        if (n < N) { int v = pre + loc[i]; rs[n] = v; cursor[n] = v; }
    }
    if (t == 0) rs[N] = E;
}

__global__ void scatter_kernel(const int* __restrict__ ei, int* __restrict__ cursor,
                               int* __restrict__ csr_src, int E) {
    int e = blockIdx.x * 256 + threadIdx.x;
    if (e >= E) return;
    int s = ei[e], d = ei[E + e];
    int pos = atomicAdd(&cursor[d], 1);
    csr_src[pos] = s;
}

// ---------------------------------------------------------------------------
// C[M x 128] = A[M x 128] @ B[128 x 128]   (B is K-major: B[k*128 + j])
// ---------------------------------------------------------------------------
__global__ __launch_bounds__(256) void gemm_nn(const float* __restrict__ A,
                                               const float* __restrict__ B,
                                               float* __restrict__ C, int M) {
    __shared__ float Bl[64 * 132];
    __shared__ float Al[32][FDIM];
    const int tid = threadIdx.x;
    const int row0 = blockIdx.x * 32;

    for (int i = tid * 4; i < 32 * FDIM; i += 1024) {
        int r = i >> 7, k = i & 127;
        int row = row0 + r;
        float4 v = make_float4(0.f, 0.f, 0.f, 0.f);
        if (row < M) v = *(const float4*)(A + (size_t)row * FDIM + k);
        *(float4*)&Al[r][k] = v;
    }

    const int jg = tid & 31, rg = tid >> 5;
    float acc[4][4] = {};

    for (int kh = 0; kh < 2; ++kh) {
        __syncthreads();
        for (int i = tid * 4; i < 64 * FDIM; i += 1024) {
            int k = i >> 7, j = i & 127;
            *(float4*)&Bl[k * 132 + j] = *(const float4*)(B + (size_t)(kh * 64 + k) * FDIM + j);
        }
        __syncthreads();
        #pragma unroll 4
        for (int k = 0; k < 64; ++k) {
            float4 b4 = *(const float4*)&Bl[k * 132 + jg * 4];
            #pragma unroll
            for (int rr = 0; rr < 4; ++rr) {
                float a = Al[rg * 4 + rr][kh * 64 + k];
                acc[rr][0] += a * b4.x; acc[rr][1] += a * b4.y;
                acc[rr][2] += a * b4.z; acc[rr][3] += a * b4.w;
            }
        }
    }
    #pragma unroll
    for (int rr = 0; rr < 4; ++rr) {
        int row = row0 + rg * 4 + rr;
        if (row < M) {
            float4 v = make_float4(acc[rr][0], acc[rr][1], acc[rr][2], acc[rr][3]);
            *(float4*)(C + (size_t)row * FDIM + jg * 4) = v;
        }
    }
}

// ---------------------------------------------------------------------------
// xgT[M][j*4+g] = (A[M x 128] @ B^T + b_ih + b_hh), TRANSPOSED output so the
// LSTM activation lane j reads one contiguous b128 {i,f,g,o}. chunk == gate.
// ---------------------------------------------------------------------------
__global__ __launch_bounds__(256) void gemm_nt_xg(const float* __restrict__ A,
                                                  const float* __restrict__ B,
                                                  const float* __restrict__ bih,
                                                  const float* __restrict__ bhh,
                                                  float* __restrict__ C, int M) {
    __shared__ float Bl[64 * 132];
    __shared__ float Al[32][FDIM];
    const int tid = threadIdx.x;
    const int row0 = blockIdx.x * 32;
    const int chunk = blockIdx.y;   // == gate index

    for (int i = tid * 4; i < 32 * FDIM; i += 1024) {
        int r = i >> 7, k = i & 127;
        int row = row0 + r;
        float4 v = make_float4(0.f, 0.f, 0.f, 0.f);
        if (row < M) v = *(const float4*)(A + (size_t)row * FDIM + k);
        *(float4*)&Al[r][k] = v;
    }

    const int jg = tid & 31, rg = tid >> 5;
    float acc[4][4] = {};

    for (int kh = 0; kh < 2; ++kh) {
        __syncthreads();
        for (int i = tid * 4; i < 128 * 64; i += 1024) {
            int g = i >> 6, kl = i & 63;
            float4 v = *(const float4*)(B + (size_t)(chunk * 128 + g) * FDIM + kh * 64 + kl);
            Bl[(kl + 0) * 132 + g] = v.x;
            Bl[(kl + 1) * 132 + g] = v.y;
            Bl[(kl + 2) * 132 + g] = v.z;
            Bl[(kl + 3) * 132 + g] = v.w;
        }
        __syncthreads();
        #pragma unroll 4
        for (int k = 0; k < 64; ++k) {
            float4 b4 = *(const float4*)&Bl[k * 132 + jg * 4];
            #pragma unroll
            for (int rr = 0; rr < 4; ++rr) {
                float a = Al[rg * 4 + rr][kh * 64 + k];
                acc[rr][0] += a * b4.x; acc[rr][1] += a * b4.y;
                acc[rr][2] += a * b4.z; acc[rr][3] += a * b4.w;
            }
        }
    }
    const int col0 = chunk * 128 + jg * 4;   // original column (gate,j) space
    float4 bsum = make_float4(bih[col0 + 0] + bhh[col0 + 0],
                              bih[col0 + 1] + bhh[col0 + 1],
                              bih[col0 + 2] + bhh[col0 + 2],
                              bih[col0 + 3] + bhh[col0 + 3]);
    float bs[4] = {bsum.x, bsum.y, bsum.z, bsum.w};
    #pragma unroll
    for (int rr = 0; rr < 4; ++rr) {
        int row = row0 + rg * 4 + rr;
        if (row < M) {
            #pragma unroll
            for (int i = 0; i < 4; ++i) {
                int j = jg * 4 + i;
                C[(size_t)row * G4H + (size_t)j * 4 + chunk] = acc[rr][i] + bs[i];
            }
        }
    }
}

// ---------------------------------------------------------------------------
// Fused GCN aggregation (CSR gather): one wave per node, registers, one write.
// ---------------------------------------------------------------------------
__global__ __launch_bounds__(256) void agg_gather(const float* __restrict__ y,
                                                  const int* __restrict__ rs,
                                                  const int* __restrict__ csr_src,
                                                  const float* __restrict__ dinv,
                                                  const float* __restrict__ bias,
                                                  float* __restrict__ o, int N) {
    const int node = blockIdx.x * 4 + (threadIdx.x >> 6);
    if (node >= N) return;
    const int lane = threadIdx.x & 63;
    const int beg = rs[node], end = rs[node + 1];
    const float dn = dinv[node];

    float2 yv = *(const float2*)(y + (size_t)node * FDIM + lane * 2);
    float2 acc = make_float2(yv.x * dn * dn, yv.y * dn * dn);

    for (int base = beg; base < end; base += 64) {
        int cnt = end - base; if (cnt > 64) cnt = 64;
        int msrc = 0; float mnrm = 0.f;
        if (lane < cnt) {
            msrc = csr_src[base + lane];
            mnrm = dinv[msrc] * dn;
        }
        for (int j = 0; j < cnt; ++j) {
            int s = __shfl(msrc, j);
            float nr = __shfl(mnrm, j);
            float2 v = *(const float2*)(y + (size_t)s * FDIM + lane * 2);
            acc.x += v.x * nr;
            acc.y += v.y * nr;
        }
    }
    float2 b = *(const float2*)(bias + lane * 2);
    acc.x = fmaxf(acc.x + b.x, 0.f);
    acc.y = fmaxf(acc.y + b.y, 0.f);
    *(float2*)(o + (size_t)node * FDIM + lane * 2) = acc;
}

// ---------------------------------------------------------------------------
// Prepack w_hh [512 x 128] fp32 into fp16 MFMA A-fragments (j-quarter layout).
// Wave w (0..3) owns ALL 4 gates for j in [32w, 32w+32): 128 rows.
// Wave-local row r = g*32 + jloc; tile rt = r>>4 = g*2 + (jloc>>4); m = r&15.
// dword idx = (((w*8 + rt)*4 + kt)*64 + lane)*4 + d
//   lane: m = lane&15, q = lane>>4; w_hh row = g*128 + 32w + 16*(rt&1) + m;
//   k = 32kt + 8q + {2d, 2d+1}.
// ---------------------------------------------------------------------------
__global__ void pack_whh(const float* __restrict__ whh, float* __restrict__ whp, int n) {
    int i = blockIdx.x * 256 + threadIdx.x;   // n = 32768 dwords
    if (i >= n) return;
    int d = i & 3, fi = i >> 2;
    int lane = fi & 63, kt = (fi >> 6) & 3, rt = (fi >> 8) & 7, w = fi >> 11;
    int m = lane & 15, q = lane >> 4;
    int g = rt >> 1;
    int r = g * FDIM + 32 * w + 16 * (rt & 1) + m;
    int k = 32 * kt + 8 * q + 2 * d;
    __half lo = __float2half(whh[r * FDIM + k]);
    __half hi = __float2half(whh[r * FDIM + k + 1]);
    unsigned u = ((unsigned)__half_as_ushort(hi) << 16) | (unsigned)__half_as_ushort(lo);
    whp[i] = __uint_as_float(u);
}

// ---------------------------------------------------------------------------
// LSTM v14: j-quarter topology — ONE barrier and TWO LDS latency legs per
// step (v9-v13 all paid 2 barriers + 4 LDS legs ≈ 1500+ cyc/step; five
// variants plateaued at 1587-1787).
// 4 waves (1/SIMD, launch_bounds(256,1) -> full 512-reg budget). Wave w owns
// all 4 gates for j in [32w,32w+32): 8 tiles x 4 kt = 32 MFMA, 128 AGPRs
// (direct-"a" asm operands). After MFMA the gate quadruple of each j is
// wave-resident: redistribute via wave-PRIVATE LDS scratch + lgkmcnt(0)
// (same-wave ordering, NO barrier), lanes 0-31 do activations for their own
// j (c_j in register), write h to double-buffered hl. xg via per-lane
// register ring (v13). The single LDS_BARRIER covers hl cross-wave.
// ---------------------------------------------------------------------------
__global__ void __launch_bounds__(256, 1)
lstm_kernel(const float* __restrict__ xgT, const float* __restrict__ whp,
            float* __restrict__ hs, int T) {
    __shared__ __align__(16) __half hl[2][FDIM];    // double-buffered h (fp16)
    __shared__ __align__(16) float scratch[4][FDIM]; // per-wave gate rows
    const int t = threadIdx.x;
    const int w = t >> 6;          // wave 0..3 = j-quarter
    const int lane = t & 63;
    const int q = lane >> 4;       // k-quad / C row-quad
    const int n = lane & 15;       // C column

    // A-fragments: all uses are "a"-constrained asm operands -> AGPR-resident.
    f16x8 aw[8][4];
    {
        const f32x4* wp4 = (const f32x4*)whp;
        #pragma unroll
        for (int rt = 0; rt < 8; ++rt) {
            #pragma unroll
            for (int kt = 0; kt < 4; ++kt) {
                frag_cast fc;
                fc.f = wp4[((w * 8 + rt) * 4 + kt) * 64 + lane];
                aw[rt][kt] = fc.h;
            }
        }
    }

    float c = 0.f;
    if (t < FDIM) hl[0][t] = __float2half(0.f);

    // xg register ring (depth 4), per-lane: lane<32 owns j = 32w + lane.
    const int j = 32 * w + lane;
    const float* xbase = xgT + (size_t)j * 4;
    f32x4 xv0, xv1, xv2, xv3;
    if (lane < 32) {
        asm volatile("global_load_dwordx4 %0, %1, off" : "=v"(xv0) : "v"(xbase + 0 * G4H));
        asm volatile("global_load_dwordx4 %0, %1, off" : "=v"(xv1) : "v"(xbase + 1 * G4H));
        asm volatile("global_load_dwordx4 %0, %1, off" : "=v"(xv2) : "v"(xbase + 2 * G4H));
        asm volatile("global_load_dwordx4 %0, %1, off" : "=v"(xv3) : "v"(xbase + 3 * G4H));
        asm volatile("s_waitcnt vmcnt(0)" ::: "memory");
    }
    __syncthreads();

#define STEP_BODY(PP, XV)                                                         \
    {                                                                             \
        const int step = s + PP;                                                  \
        const __half* hsrc = hl[step & 1];                                        \
        f16x8 bb[4];                                                              \
        {                                                                         \
            frag_cast bc;                                                         \
            bc.f = *(const f32x4*)((const char*)hsrc +   0 + q * 16); bb[0] = bc.h;\
            bc.f = *(const f32x4*)((const char*)hsrc +  64 + q * 16); bb[1] = bc.h;\
            bc.f = *(const f32x4*)((const char*)hsrc + 128 + q * 16); bb[2] = bc.h;\
            bc.f = *(const f32x4*)((const char*)hsrc + 192 + q * 16); bb[3] = bc.h;\
        }                                                                         \
        f32x4 cd[8];                                                              \
        _Pragma("unroll")                                                         \
        for (int rt = 0; rt < 8; ++rt) cd[rt] = f32x4{0.f, 0.f, 0.f, 0.f};        \
        _Pragma("unroll")                                                         \
        for (int kt = 0; kt < 4; ++kt) {                                          \
            _Pragma("unroll")                                                     \
            for (int rt = 0; rt < 8; ++rt)                                        \
                asm volatile("v_mfma_f32_16x16x32_f16 %0, %1, %2, %0"             \
                             : "+v"(cd[rt]) : "a"(aw[rt][kt]), "v"(bb[kt]));      \
        }                                                                         \
        asm volatile("s_nop 7\n\ts_nop 7" ::: "memory");                          \
        {                                                                         \
            int nl = n & 3;                                                       \
            f32x4 selA = (nl == 0) ? cd[0] : (nl == 1) ? cd[1]                    \
                       : (nl == 2) ? cd[2] : cd[3];                               \
            f32x4 selB = (nl == 0) ? cd[4] : (nl == 1) ? cd[5]                    \
                       : (nl == 2) ? cd[6] : cd[7];                               \
            f32x4 sel = (n < 4) ? selA : selB;                                    \
            if (n < 8)                                                            \
                *(f32x4*)&scratch[w][n * 16 + 4 * q] = sel;                       \
        }                                                                         \
        asm volatile("s_waitcnt lgkmcnt(0)" ::: "memory");  /* wave-local */      \
        if (lane < 32) {                                                          \
            asm volatile("s_waitcnt vmcnt(4)" : "+v"(XV));                        \
            float gi = scratch[w][      lane] + XV.x;                             \
            float gf = scratch[w][ 32 + lane] + XV.y;                             \
            float gg = scratch[w][ 64 + lane] + XV.z;                             \
            float go = scratch[w][ 96 + lane] + XV.w;                             \
            int nid = step + 4; if (nid > T - 1) nid = T - 1;                     \
            asm volatile("global_load_dwordx4 %0, %1, off"                        \
                         : "=v"(XV) : "v"(xbase + (size_t)nid * G4H));            \
            gi = 1.f / (1.f + __expf(-gi));                                       \
            gf = 1.f / (1.f + __expf(-gf));                                       \
            gg = 1.f - 2.f / (1.f + __expf(2.f * gg));                            \
            go = 1.f / (1.f + __expf(-go));                                       \
            c = gf * c + gi * gg;                                                 \
            float th = 1.f - 2.f / (1.f + __expf(2.f * c));                       \
            float h = go * th;                                                    \
            hs[(size_t)step * FDIM + j] = h;                                      \
            hl[(step + 1) & 1][j] = __float2half(h);                              \
        }                                                                         \
        LDS_BARRIER();   /* the ONLY barrier: covers hl cross-wave */             \
    }

    for (int s = 0; s < T; s += 4) {
        STEP_BODY(0, xv0)
        STEP_BODY(1, xv1)
        STEP_BODY(2, xv2)
        STEP_BODY(3, xv3)
    }
#undef STEP_BODY
}

// ---------------------------------------------------------------------------
// out[M x 12] = hs[M x 128] @ w_fc^T + b_fc
// ---------------------------------------------------------------------------
__global__ __launch_bounds__(256) void fc_kernel(const float* __restrict__ hs,
                                                 const float* __restrict__ wfc,
                                                 const float* __restrict__ bfc,
                                                 float* __restrict__ out, int M) {
    __shared__ float wl[12 * FDIM];
    __shared__ float bl[12];
    const int tid = threadIdx.x;
    for (int i = tid; i < 12 * FDIM / 4; i += 256)
        ((float4*)wl)[i] = ((const float4*)wfc)[i];
    if (tid < 12) bl[tid] = bfc[tid];
    __syncthreads();

    int i = blockIdx.x * 256 + tid;
    if (i >= M) return;
    const float* hrow = hs + (size_t)i * FDIM;
    float acc[12];
    #pragma unroll
    for (int t = 0; t < 12; ++t) acc[t] = bl[t];
    for (int k = 0; k < FDIM; k += 4) {
        float4 h4 = *(const float4*)(hrow + k);
        #pragma unroll
        for (int t = 0; t < 12; ++t) {
            acc[t] += h4.x * wl[t * FDIM + k] + h4.y * wl[t * FDIM + k + 1]
                    + h4.z * wl[t * FDIM + k + 2] + h4.w * wl[t * FDIM + k + 3];
        }
    }
    #pragma unroll
    for (int t = 0; t < 12; ++t) out[(size_t)i * 12 + t] = acc[t];
}

// ---------------------------------------------------------------------------
extern "C" void kernel_launch(void* const* d_in, const int* in_sizes, int n_in,
                              void* d_out, int out_size, void* d_ws, size_t ws_size,
                              hipStream_t stream) {
    const float* x    = (const float*)d_in[0];
    const int*   ei   = (const int*)  d_in[1];
    const float* W1   = (const float*)d_in[2];
    const float* b1   = (const float*)d_in[3];
    const float* W2   = (const float*)d_in[4];
    const float* b2   = (const float*)d_in[5];
    const float* w_ih = (const float*)d_in[6];
    const float* w_hh = (const float*)d_in[7];
    const float* b_ih = (const float*)d_in[8];
    const float* b_hh = (const float*)d_in[9];
    const float* w_fc = (const float*)d_in[10];
    const float* b_fc = (const float*)d_in[11];

    const int N = in_sizes[0] / FDIM;     // 20000
    const int E = in_sizes[1] / 2;        // 1280000

    float* ws   = (float*)d_ws;
    int*   deg  = (int*)ws;                       // 20480 ints
    float* dinv = ws + 20480;                     // 20480 floats
    float* whp  = ws + 40960;                     // 32768 dwords (packed fragments)
    int*   rs   = (int*)(ws + 73728);             // 20992 ints (N+1 used)
    int*   cur  = (int*)(ws + 94720);             // 20480 ints
    int*   csr  = (int*)(ws + 115200);            // E ints
    float* hB   = ws + 115200 + 1280000;          // N*128
    float* big  = hB + (size_t)N * FDIM;          // xg region (N*512), aliases y/hA
    float* y    = big;                            // N*128 (dead before xg written)
    float* hA   = big + (size_t)N * FDIM;         // h1   (dead before xg written)
    float* xg   = big;                            // N*512 (transposed [node][j*4+g])
    float* hs   = big + (size_t)N * G4H;          // N*128

    hipMemsetAsync(deg, 0, (size_t)N * sizeof(int), stream);
    deg_kernel<<<(E + 255) / 256, 256, 0, stream>>>(ei, deg, E);
    dinv_kernel<<<(N + 255) / 256, 256, 0, stream>>>(deg, dinv, N);
    scan_kernel<<<1, 1024, 0, stream>>>(deg, rs, cur, N, E);
    scatter_kernel<<<(E + 255) / 256, 256, 0, stream>>>(ei, cur, csr, E);
    pack_whh<<<(32768 + 255) / 256, 256, 0, stream>>>(w_hh, whp, 32768);

    const int gblocks = (N + 31) / 32;
    const int ablocks = (N + 3) / 4;
    // layer 1
    gemm_nn<<<gblocks, 256, 0, stream>>>(x, W1, y, N);
    agg_gather<<<ablocks, 256, 0, stream>>>(y, rs, csr, dinv, b1, hA, N);
    // layer 2
    gemm_nn<<<gblocks, 256, 0, stream>>>(hA, W2, y, N);
    agg_gather<<<ablocks, 256, 0, stream>>>(y, rs, csr, dinv, b2, hB, N);
    // LSTM input projection (transposed output)
    gemm_nt_xg<<<dim3(gblocks, 4), 256, 0, stream>>>(hB, w_ih, b_ih, b_hh, xg, N);
    // sequential LSTM (single CU — the critical path)
    lstm_kernel<<<1, 256, 0, stream>>>(xg, whp, hs, N);
    // final projection
    fc_kernel<<<(N + 255) / 256, 256, 0, stream>>>(hs, w_fc, b_fc, (float*)d_out, N);
}

// Round 15
// 13565.594 us; speedup vs baseline: 1.1274x; 1.1274x over previous
//
#include <hip/hip_runtime.h>
#include <hip/hip_bf16.h>
#include <hip/hip_fp16.h>

// Problem constants (fixed by the reference)
#define FDIM 128      // F_IN == H == 128
#define G4H  512      // 4*H

typedef float f32x4 __attribute__((ext_vector_type(4)));
typedef _Float16 f16x8 __attribute__((ext_vector_type(8)));

union frag_cast { f32x4 f; f16x8 h; };

// LDS-only barrier: does NOT drain vmcnt (global ops stay in flight).
#define LDS_BARRIER() asm volatile("s_waitcnt lgkmcnt(0)\n\ts_barrier" ::: "memory")

#define AS1 __attribute__((address_space(1)))
#define AS3 __attribute__((address_space(3)))
// Async global->LDS, 16B/lane: LDS dst = uniform base + lane*16.
__device__ __forceinline__ void load_lds16(const float* g, float* l) {
    __builtin_amdgcn_global_load_lds((const AS1 unsigned int*)g,
                                     (AS3 unsigned int*)l, 16, 0, 0);
}

// ---------------------------------------------------------------------------
// degree / normalization
// ---------------------------------------------------------------------------
__global__ void deg_kernel(const int* __restrict__ ei, int* __restrict__ deg, int E) {
    int e = blockIdx.x * 256 + threadIdx.x;
    if (e < E) atomicAdd(&deg[ei[E + e]], 1);
}

__global__ void dinv_kernel(const int* __restrict__ deg, float* __restrict__ dinv, int N) {
    int n = blockIdx.x * 256 + threadIdx.x;
    if (n < N) dinv[n] = rsqrtf((float)(deg[n] + 1));   // +1 self-loop
}

// ---------------------------------------------------------------------------
// CSR build: exclusive scan of deg (1024 thr x 20 nodes), then edge scatter.
// ---------------------------------------------------------------------------
__global__ __launch_bounds__(1024) void scan_kernel(const int* __restrict__ deg,
                                                    int* __restrict__ rs,
                                                    int* __restrict__ cursor,
                                                    int N, int E) {
    __shared__ int buf[2][1024];
    const int t = threadIdx.x;
    const int base = t * 20;
    int loc[20]; int s = 0;
    #pragma unroll
    for (int i = 0; i < 20; ++i) {
        int n = base + i;
        int d = (n < N) ? deg[n] : 0;
        loc[i] = s; s += d;
    }
    buf[0][t] = s; __syncthreads();
    int pb = 0;
    for (int off = 1; off < 1024; off <<= 1) {
        int v = buf[pb][t] + ((t >= off) ? buf[pb][t - off] : 0);
        buf[pb ^ 1][t] = v; pb ^= 1; __syncthreads();
    }
    int pre = (t > 0) ? buf[pb][t - 1] : 0;   // exclusive prefix
    #pragma unroll
    for (int i = 0; i < 20; ++i) {
        int n = base + i;
        if (n < N) { int v = pre + loc[i]; rs[n] = v; cursor[n] = v; }
    }
    if (t == 0) rs[N] = E;
}

__global__ void scatter_kernel(const int* __restrict__ ei, int* __restrict__ cursor,
                               int* __restrict__ csr_src, int E) {
    int e = blockIdx.x * 256 + threadIdx.x;
    if (e >= E) return;
    int s = ei[e], d = ei[E + e];
    int pos = atomicAdd(&cursor[d], 1);
    csr_src[pos] = s;
}

// ---------------------------------------------------------------------------
// C[M x 128] = A[M x 128] @ B[128 x 128]   (B is K-major: B[k*128 + j])
// ---------------------------------------------------------------------------
__global__ __launch_bounds__(256) void gemm_nn(const float* __restrict__ A,
                                               const float* __restrict__ B,
                                               float* __restrict__ C, int M) {
    __shared__ float Bl[64 * 132];
    __shared__ float Al[32][FDIM];
    const int tid = threadIdx.x;
    const int row0 = blockIdx.x * 32;

    for (int i = tid * 4; i < 32 * FDIM; i += 1024) {
        int r = i >> 7, k = i & 127;
        int row = row0 + r;
        float4 v = make_float4(0.f, 0.f, 0.f, 0.f);
        if (row < M) v = *(const float4*)(A + (size_t)row * FDIM + k);
        *(float4*)&Al[r][k] = v;
    }

    const int jg = tid & 31, rg = tid >> 5;
    float acc[4][4] = {};

    for (int kh = 0; kh < 2; ++kh) {
        __syncthreads();
        for (int i = tid * 4; i < 64 * FDIM; i += 1024) {
            int k = i >> 7, j = i & 127;
            *(float4*)&Bl[k * 132 + j] = *(const float4*)(B + (size_t)(kh * 64 + k) * FDIM + j);
        }
        __syncthreads();
        #pragma unroll 4
        for (int k = 0; k < 64; ++k) {
            float4 b4 = *(const float4*)&Bl[k * 132 + jg * 4];
            #pragma unroll
            for (int rr = 0; rr < 4; ++rr) {
                float a = Al[rg * 4 + rr][kh * 64 + k];
                acc[rr][0] += a * b4.x; acc[rr][1] += a * b4.y;
                acc[rr][2] += a * b4.z; acc[rr][3] += a * b4.w;
            }
        }
    }
    #pragma unroll
    for (int rr = 0; rr < 4; ++rr) {
        int row = row0 + rg * 4 + rr;
        if (row < M) {
            float4 v = make_float4(acc[rr][0], acc[rr][1], acc[rr][2], acc[rr][3]);
            *(float4*)(C + (size_t)row * FDIM + jg * 4) = v;
        }
    }
}

// ---------------------------------------------------------------------------
// xg[M x 512] = A[M x 128] @ B^T  (+ b_ih + b_hh), B is [512 x 128] row-major.
// Output layout [step][gate*128 + j] (what the v9 LSTM expects).
// ---------------------------------------------------------------------------
__global__ __launch_bounds__(256) void gemm_nt_xg(const float* __restrict__ A,
                                                  const float* __restrict__ B,
                                                  const float* __restrict__ bih,
                                                  const float* __restrict__ bhh,
                                                  float* __restrict__ C, int M) {
    __shared__ float Bl[64 * 132];
    __shared__ float Al[32][FDIM];
    const int tid = threadIdx.x;
    const int row0 = blockIdx.x * 32;
    const int chunk = blockIdx.y;

    for (int i = tid * 4; i < 32 * FDIM; i += 1024) {
        int r = i >> 7, k = i & 127;
        int row = row0 + r;
        float4 v = make_float4(0.f, 0.f, 0.f, 0.f);
        if (row < M) v = *(const float4*)(A + (size_t)row * FDIM + k);
        *(float4*)&Al[r][k] = v;
    }

    const int jg = tid & 31, rg = tid >> 5;
    float acc[4][4] = {};

    for (int kh = 0; kh < 2; ++kh) {
        __syncthreads();
        for (int i = tid * 4; i < 128 * 64; i += 1024) {
            int g = i >> 6, kl = i & 63;
            float4 v = *(const float4*)(B + (size_t)(chunk * 128 + g) * FDIM + kh * 64 + kl);
            Bl[(kl + 0) * 132 + g] = v.x;
            Bl[(kl + 1) * 132 + g] = v.y;
            Bl[(kl + 2) * 132 + g] = v.z;
            Bl[(kl + 3) * 132 + g] = v.w;
        }
        __syncthreads();
        #pragma unroll 4
        for (int k = 0; k < 64; ++k) {
            float4 b4 = *(const float4*)&Bl[k * 132 + jg * 4];
            #pragma unroll
            for (int rr = 0; rr < 4; ++rr) {
                float a = Al[rg * 4 + rr][kh * 64 + k];
                acc[rr][0] += a * b4.x; acc[rr][1] += a * b4.y;
                acc[rr][2] += a * b4.z; acc[rr][3] += a * b4.w;
            }
        }
    }
    const int col0 = chunk * 128 + jg * 4;
    float4 bsum = make_float4(bih[col0 + 0] + bhh[col0 + 0],
                              bih[col0 + 1] + bhh[col0 + 1],
                              bih[col0 + 2] + bhh[col0 + 2],
                              bih[col0 + 3] + bhh[col0 + 3]);
    #pragma unroll
    for (int rr = 0; rr < 4; ++rr) {
        int row = row0 + rg * 4 + rr;
        if (row < M) {
            float4 v = make_float4(acc[rr][0] + bsum.x, acc[rr][1] + bsum.y,
                                   acc[rr][2] + bsum.z, acc[rr][3] + bsum.w);
            *(float4*)(C + (size_t)row * G4H + col0) = v;
        }
    }
}

// ---------------------------------------------------------------------------
// Fused GCN aggregation (CSR gather): one wave per node, registers, one write.
// ---------------------------------------------------------------------------
__global__ __launch_bounds__(256) void agg_gather(const float* __restrict__ y,
                                                  const int* __restrict__ rs,
                                                  const int* __restrict__ csr_src,
                                                  const float* __restrict__ dinv,
                                                  const float* __restrict__ bias,
                                                  float* __restrict__ o, int N) {
    const int node = blockIdx.x * 4 + (threadIdx.x >> 6);
    if (node >= N) return;
    const int lane = threadIdx.x & 63;
    const int beg = rs[node], end = rs[node + 1];
    const float dn = dinv[node];

    float2 yv = *(const float2*)(y + (size_t)node * FDIM + lane * 2);
    float2 acc = make_float2(yv.x * dn * dn, yv.y * dn * dn);

    for (int base = beg; base < end; base += 64) {
        int cnt = end - base; if (cnt > 64) cnt = 64;
        int msrc = 0; float mnrm = 0.f;
        if (lane < cnt) {
            msrc = csr_src[base + lane];
            mnrm = dinv[msrc] * dn;
        }
        for (int j = 0; j < cnt; ++j) {
            int s = __shfl(msrc, j);
            float nr = __shfl(mnrm, j);
            float2 v = *(const float2*)(y + (size_t)s * FDIM + lane * 2);
            acc.x += v.x * nr;
            acc.y += v.y * nr;
        }
    }
    float2 b = *(const float2*)(bias + lane * 2);
    acc.x = fmaxf(acc.x + b.x, 0.f);
    acc.y = fmaxf(acc.y + b.y, 0.f);
    *(float2*)(o + (size_t)node * FDIM + lane * 2) = acc;
}

// ---------------------------------------------------------------------------
// Prepack w_hh [512 x 128] fp32 into fp16 MFMA A-fragments (8-wave layout).
// dword idx = (((w*4+rt)*4+kt)*64 + lane)*4 + d
//   wave w (0..7): gate rows [64w, 64w+64); row-tile rt (0..3);
//   lane: m = lane&15, q = lane>>4; row r = 64w+16rt+m; k = 32kt+8q+{2d,2d+1}.
// ---------------------------------------------------------------------------
__global__ void pack_whh(const float* __restrict__ whh, float* __restrict__ whp, int n) {
    int i = blockIdx.x * 256 + threadIdx.x;   // n = 32768 dwords
    if (i >= n) return;
    int d = i & 3, fi = i >> 2;
    int lane = fi & 63, kt = (fi >> 6) & 3, rt = (fi >> 8) & 3, w = fi >> 10;
    int m = lane & 15, q = lane >> 4;
    int r = 64 * w + 16 * rt + m;
    int k = 32 * kt + 8 * q + 2 * d;
    __half lo = __float2half(whh[r * FDIM + k]);
    __half hi = __float2half(whh[r * FDIM + k + 1]);
    unsigned u = ((unsigned)__half_as_ushort(hi) << 16) | (unsigned)__half_as_ushort(lo);
    whp[i] = __uint_as_float(u);
}

// ---------------------------------------------------------------------------
// LSTM v15 = v9 VERBATIM (the measured-best LSTM: 13.22 ms across 14 rounds).
// 8 waves; builtin MFMA on "=a"-pinned fp16 A-frags (builtin beat direct-asm
// v12 by 0.7 ms — the accvgpr copies overlap harmlessly); 2 LDS-only
// barriers; gates via LDS; phase B on 2 waves; wave-2 streams xg into a
// 4-slot LDS ring via global_load_lds (vmcnt(6) = only vm wait in the loop).
// v10/v11/v13/v14 structural variants (4-wave, 1-barrier, bpermute,
// register-ring xg, j-quarter) all measured WORSE (1670-2352 cyc/step vs
// 1587); the residual ~700 cyc over the chain model is post-barrier LDS
// broadcast queuing + barrier cost at low occupancy — unresolved, but every
// attempt to restructure it regressed.
// ---------------------------------------------------------------------------
__global__ void __launch_bounds__(512, 2)
lstm_kernel(const float* __restrict__ xg, const float* __restrict__ whp,
            float* __restrict__ hs, int T) {
    __shared__ __align__(16) __half hl[FDIM];
    __shared__ __align__(16) float gates[4 * 136];   // stride 136 floats per gate
    __shared__ __align__(16) float xr[4][G4H];       // xg ring, slot = step & 3
    const int t = threadIdx.x;
    const int w = t >> 6;          // wave 0..7
    const int lane = t & 63;
    const int q = lane >> 4;       // k-quad / C row-quad
    const int n = lane & 15;       // C column

    // Load + pin A-fragments into AGPRs: aw[rt][kt], 4 dwords (8 fp16) each.
    f16x8 aw[4][4];
    {
        const f32x4* wp4 = (const f32x4*)whp;
        #pragma unroll
        for (int rt = 0; rt < 4; ++rt) {
            #pragma unroll
            for (int kt = 0; kt < 4; ++kt) {
                frag_cast fc;
                fc.f = wp4[((w * 4 + rt) * 4 + kt) * 64 + lane];
                f16x8 tmp = fc.h;
                asm volatile("" : "=a"(aw[rt][kt]) : "0"(tmp));  // pin to AGPR class
            }
        }
    }

    float c = 0.f;
    if (t < FDIM) hl[t] = __float2half(0.f);
    // Prime the xg ring: slots 0..2 (6 outstanding vm ops on wave 2).
    if (w == 2) {
        #pragma unroll
        for (int i = 0; i < 3; ++i) {
            const float* g0 = xg + (size_t)i * G4H + lane * 4;
            load_lds16(g0,       &xr[i][0]);
            load_lds16(g0 + 256, &xr[i][256]);
        }
    }
    __syncthreads();   // pre-loop: full barrier is fine (vm ops above have slack)

    const int gsel = w >> 1;                      // this wave's gate
    const int j0 = (w & 1) * 64 + 16 * n + 4 * q; // writeout j (lanes n<4)

    for (int step = 0; step < T; ++step) {
        // ---- phase A: MFMA GEMV, all 8 waves ----
        f32x4 cd0 = {0.f, 0.f, 0.f, 0.f}, cd1 = cd0, cd2 = cd0, cd3 = cd0;
        #pragma unroll
        for (int kt = 0; kt < 4; ++kt) {
            // B-frag: h[32kt + 8q .. +8) broadcast to all 16 columns.
            frag_cast bc;
            bc.f = *(const f32x4*)((const char*)hl + kt * 64 + q * 16);
            f16x8 b = bc.h;
            cd0 = __builtin_amdgcn_mfma_f32_16x16x32_f16(aw[0][kt], b, cd0, 0, 0, 0);
            cd1 = __builtin_amdgcn_mfma_f32_16x16x32_f16(aw[1][kt], b, cd1, 0, 0, 0);
            cd2 = __builtin_amdgcn_mfma_f32_16x16x32_f16(aw[2][kt], b, cd2, 0, 0, 0);
            cd3 = __builtin_amdgcn_mfma_f32_16x16x32_f16(aw[3][kt], b, cd3, 0, 0, 0);
        }
        // Every C column holds the same values; lanes n<4 write row-tile rt=n.
        f32x4 sel = (n == 0) ? cd0 : (n == 1) ? cd1 : (n == 2) ? cd2 : cd3;
        if (n < 4)
            *(f32x4*)&gates[gsel * 136 + j0] = sel;

        // ---- wave 2: stream xg[step+3] into ring slot (step+3)&3 ----
        if (w == 2) {
            int idx = step + 3; if (idx >= T) idx = T - 1;
            const float* g0 = xg + (size_t)idx * G4H + lane * 4;
            load_lds16(g0,       &xr[idx & 3][0]);
            load_lds16(g0 + 256, &xr[idx & 3][256]);
            // guarantee slot step&3 (issued 3 steps ago) has landed
            asm volatile("s_waitcnt vmcnt(6)" ::: "memory");
        }
        LDS_BARRIER();

        // ---- phase B: 2 waves, thread j: combine + activations + state ----
        if (t < FDIM) {
            const float* xs = xr[step & 3];
            float gi = gates[0 * 136 + t] + xs[0 * FDIM + t];
            float gf = gates[1 * 136 + t] + xs[1 * FDIM + t];
            float gg = gates[2 * 136 + t] + xs[2 * FDIM + t];
            float go = gates[3 * 136 + t] + xs[3 * FDIM + t];
            gi = 1.f / (1.f + __expf(-gi));
            gf = 1.f / (1.f + __expf(-gf));
            gg = 1.f - 2.f / (1.f + __expf(2.f * gg));
            go = 1.f / (1.f + __expf(-go));
            c = gf * c + gi * gg;
            float th = 1.f - 2.f / (1.f + __expf(2.f * c));
            float h = go * th;
            hs[(size_t)step * FDIM + t] = h;   // store: never waited on in-loop
            hl[t] = __float2half(h);
        }
        LDS_BARRIER();
    }
}

// ---------------------------------------------------------------------------
// out[M x 12] = hs[M x 128] @ w_fc^T + b_fc
// ---------------------------------------------------------------------------
__global__ __launch_bounds__(256) void fc_kernel(const float* __restrict__ hs,
                                                 const float* __restrict__ wfc,
                                                 const float* __restrict__ bfc,
                                                 float* __restrict__ out, int M) {
    __shared__ float wl[12 * FDIM];
    __shared__ float bl[12];
    const int tid = threadIdx.x;
    for (int i = tid; i < 12 * FDIM / 4; i += 256)
        ((float4*)wl)[i] = ((const float4*)wfc)[i];
    if (tid < 12) bl[tid] = bfc[tid];
    __syncthreads();

    int i = blockIdx.x * 256 + tid;
    if (i >= M) return;
    const float* hrow = hs + (size_t)i * FDIM;
    float acc[12];
    #pragma unroll
    for (int t = 0; t < 12; ++t) acc[t] = bl[t];
    for (int k = 0; k < FDIM; k += 4) {
        float4 h4 = *(const float4*)(hrow + k);
        #pragma unroll
        for (int t = 0; t < 12; ++t) {
            acc[t] += h4.x * wl[t * FDIM + k] + h4.y * wl[t * FDIM + k + 1]
                    + h4.z * wl[t * FDIM + k + 2] + h4.w * wl[t * FDIM + k + 3];
        }
    }
    #pragma unroll
    for (int t = 0; t < 12; ++t) out[(size_t)i * 12 + t] = acc[t];
}

// ---------------------------------------------------------------------------
extern "C" void kernel_launch(void* const* d_in, const int* in_sizes, int n_in,
                              void* d_out, int out_size, void* d_ws, size_t ws_size,
                              hipStream_t stream) {
    const float* x    = (const float*)d_in[0];
    const int*   ei   = (const int*)  d_in[1];
    const float* W1   = (const float*)d_in[2];
    const float* b1   = (const float*)d_in[3];
    const float* W2   = (const float*)d_in[4];
    const float* b2   = (const float*)d_in[5];
    const float* w_ih = (const float*)d_in[6];
    const float* w_hh = (const float*)d_in[7];
    const float* b_ih = (const float*)d_in[8];
    const float* b_hh = (const float*)d_in[9];
    const float* w_fc = (const float*)d_in[10];
    const float* b_fc = (const float*)d_in[11];

    const int N = in_sizes[0] / FDIM;     // 20000
    const int E = in_sizes[1] / 2;        // 1280000

    float* ws   = (float*)d_ws;
    int*   deg  = (int*)ws;                       // 20480 ints
    float* dinv = ws + 20480;                     // 20480 floats
    float* whp  = ws + 40960;                     // 32768 dwords (packed fragments)
    int*   rs   = (int*)(ws + 73728);             // 20992 ints (N+1 used)
    int*   cur  = (int*)(ws + 94720);             // 20480 ints
    int*   csr  = (int*)(ws + 115200);            // E ints
    float* hB   = ws + 115200 + 1280000;          // N*128
    float* big  = hB + (size_t)N * FDIM;          // xg region (N*512), aliases y/hA
    float* y    = big;                            // N*128 (dead before xg written)
    float* hA   = big + (size_t)N * FDIM;         // h1   (dead before xg written)
    float* xg   = big;                            // N*512 ([step][gate*128+j])
    float* hs   = big + (size_t)N * G4H;          // N*128

    hipMemsetAsync(deg, 0, (size_t)N * sizeof(int), stream);
    deg_kernel<<<(E + 255) / 256, 256, 0, stream>>>(ei, deg, E);
    dinv_kernel<<<(N + 255) / 256, 256, 0, stream>>>(deg, dinv, N);
    scan_kernel<<<1, 1024, 0, stream>>>(deg, rs, cur, N, E);
    scatter_kernel<<<(E + 255) / 256, 256, 0, stream>>>(ei, cur, csr, E);
    pack_whh<<<(32768 + 255) / 256, 256, 0, stream>>>(w_hh, whp, 32768);

    const int gblocks = (N + 31) / 32;
    const int ablocks = (N + 3) / 4;
    // layer 1
    gemm_nn<<<gblocks, 256, 0, stream>>>(x, W1, y, N);
    agg_gather<<<ablocks, 256, 0, stream>>>(y, rs, csr, dinv, b1, hA, N);
    // layer 2
    gemm_nn<<<gblocks, 256, 0, stream>>>(hA, W2, y, N);
    agg_gather<<<ablocks, 256, 0, stream>>>(y, rs, csr, dinv, b2, hB, N);
    // LSTM input projection
    gemm_nt_xg<<<dim3(gblocks, 4), 256, 0, stream>>>(hB, w_ih, b_ih, b_hh, xg, N);
    // sequential LSTM (single CU — the critical path)
    lstm_kernel<<<1, 512, 0, stream>>>(xg, whp, hs, N);
    // final projection
    fc_kernel<<<(N + 255) / 256, 256, 0, stream>>>(hs, w_fc, b_fc, (float*)d_out, N);
}